// Round 7
// baseline (80.250 us; speedup 1.0000x reference)
//
#include <hip/hip_runtime.h>

#define BS 256

typedef float f32x4 __attribute__((ext_vector_type(4)));
typedef unsigned int u32x4 __attribute__((ext_vector_type(4)));

__device__ __forceinline__ f32x4 splat4(float v) {
  f32x4 r; r[0] = v; r[1] = v; r[2] = v; r[3] = v; return r;
}
__device__ __forceinline__ f32x4 pkfma(float w, f32x4 x, f32x4 a) {
  return __builtin_elementwise_fma(splat4(w), x, a);
}

// tanh via Pade[7/6] (continued-fraction convergent), zero transcendentals.
// tanh(x) ~= x*(t^3+378t^2+17325t+135135)/(28t^3+3150t^2+62370t+135135), t=x^2
// |err| <= ~1e-4 on [-6,6]; overshoot past |x|~4.9 capped by med3 to [-1,1].
// Division by Newton rcp (bit-hack init ~5% err, 3 iters).
__device__ __forceinline__ f32x4 tanh_pade(f32x4 x) {
  f32x4 a;
#pragma unroll
  for (int e = 0; e < 4; ++e) a[e] = __builtin_amdgcn_fmed3f(x[e], -6.0f, 6.0f);
  f32x4 t = a * a;
  f32x4 n = t + 378.0f;
  n = __builtin_elementwise_fma(n, t, splat4(17325.0f));
  n = __builtin_elementwise_fma(n, t, splat4(135135.0f));
  n = n * a;
  f32x4 d = __builtin_elementwise_fma(t, splat4(28.0f), splat4(3150.0f));
  d = __builtin_elementwise_fma(d, t, splat4(62370.0f));
  d = __builtin_elementwise_fma(d, t, splat4(135135.0f));
  // d in [1.35e5, 7.8e6]; bit-hack reciprocal + 3 Newton iterations
  u32x4 bi = __builtin_bit_cast(u32x4, d);
  u32x4 yi = 0x7EF311C3u - bi;
  f32x4 y = __builtin_bit_cast(f32x4, yi);
#pragma unroll
  for (int it = 0; it < 3; ++it) {
    f32x4 u = __builtin_elementwise_fma(-d, y, splat4(2.0f));
    y = y * u;
  }
  f32x4 r = n * y;
#pragma unroll
  for (int e = 0; e < 4; ++e) r[e] = __builtin_amdgcn_fmed3f(r[e], -1.0f, 1.0f);
  return r;
}

__device__ __forceinline__ f32x4 fast_sigmoid4(f32x4 x) {
  f32x4 z = x * -1.4426950408889634f;
  f32x4 t;
#pragma unroll
  for (int e = 0; e < 4; ++e) t[e] = __builtin_amdgcn_exp2f(z[e]);
  f32x4 tp1 = t + 1.0f;
  f32x4 r;
#pragma unroll
  for (int e = 0; e < 4; ++e) r[e] = __builtin_amdgcn_rcpf(tp1[e]);
  return r;
}
__device__ __forceinline__ f32x4 relu4(f32x4 x) {
  return __builtin_elementwise_max(x, splat4(0.0f));
}

// nested packed-fma dot products (round-4 proven structure, splat2 -> splat4)
#define D4(W, B, O, p0, p1, p2, p3)                                            \
  pkfma((W)[(O)*4 + 0], p0,                                                    \
  pkfma((W)[(O)*4 + 1], p1,                                                    \
  pkfma((W)[(O)*4 + 2], p2,                                                    \
  pkfma((W)[(O)*4 + 3], p3, splat4((B)[O])))))

#define D8(W, B, O, p0, p1, p2, p3, p4, p5, p6, p7)                            \
  pkfma((W)[(O)*8 + 0], p0,                                                    \
  pkfma((W)[(O)*8 + 1], p1,                                                    \
  pkfma((W)[(O)*8 + 2], p2,                                                    \
  pkfma((W)[(O)*8 + 3], p3,                                                    \
  pkfma((W)[(O)*8 + 4], p4,                                                    \
  pkfma((W)[(O)*8 + 5], p5,                                                    \
  pkfma((W)[(O)*8 + 6], p6,                                                    \
  pkfma((W)[(O)*8 + 7], p7, splat4((B)[O])))))))))

#define D12(W, B, O, p0, p1, p2, p3, p4, p5, p6, p7, p8, p9, pa, pb)           \
  pkfma((W)[(O)*12 + 0], p0,                                                   \
  pkfma((W)[(O)*12 + 1], p1,                                                   \
  pkfma((W)[(O)*12 + 2], p2,                                                   \
  pkfma((W)[(O)*12 + 3], p3,                                                   \
  pkfma((W)[(O)*12 + 4], p4,                                                   \
  pkfma((W)[(O)*12 + 5], p5,                                                   \
  pkfma((W)[(O)*12 + 6], p6,                                                   \
  pkfma((W)[(O)*12 + 7], p7,                                                   \
  pkfma((W)[(O)*12 + 8], p8,                                                   \
  pkfma((W)[(O)*12 + 9], p9,                                                   \
  pkfma((W)[(O)*12 +10], pa,                                                   \
  pkfma((W)[(O)*12 +11], pb, splat4((B)[O])))))))))))))

#define D16(W, B, O, p0, p1, p2, p3, p4, p5, p6, p7, p8, p9, pa, pb, pc, pd, pe, pf) \
  pkfma((W)[(O)*16 + 0], p0,                                                   \
  pkfma((W)[(O)*16 + 1], p1,                                                   \
  pkfma((W)[(O)*16 + 2], p2,                                                   \
  pkfma((W)[(O)*16 + 3], p3,                                                   \
  pkfma((W)[(O)*16 + 4], p4,                                                   \
  pkfma((W)[(O)*16 + 5], p5,                                                   \
  pkfma((W)[(O)*16 + 6], p6,                                                   \
  pkfma((W)[(O)*16 + 7], p7,                                                   \
  pkfma((W)[(O)*16 + 8], p8,                                                   \
  pkfma((W)[(O)*16 + 9], p9,                                                   \
  pkfma((W)[(O)*16 +10], pa,                                                   \
  pkfma((W)[(O)*16 +11], pb,                                                   \
  pkfma((W)[(O)*16 +12], pc,                                                   \
  pkfma((W)[(O)*16 +13], pd,                                                   \
  pkfma((W)[(O)*16 +14], pe,                                                   \
  pkfma((W)[(O)*16 +15], pf, splat4((B)[O])))))))))))))))))

__global__ void __launch_bounds__(BS) qcnn_pade(
    const float* __restrict__ inp,
    const float* __restrict__ fm_w,  const float* __restrict__ fm_b,
    const float* __restrict__ c1_w,  const float* __restrict__ c1_b,
    const float* __restrict__ p1_w,  const float* __restrict__ p1_b,
    const float* __restrict__ c2_w,  const float* __restrict__ c2_b,
    const float* __restrict__ p2_w,  const float* __restrict__ p2_b,
    const float* __restrict__ c3_w,  const float* __restrict__ c3_b,
    const float* __restrict__ v_w,   const float* __restrict__ v_b,
    const float* __restrict__ o_w,   const float* __restrict__ o_b,
    const float* __restrict__ ln1_w, const float* __restrict__ ln1_b,
    const float* __restrict__ ln2_w, const float* __restrict__ ln2_b,
    const float* __restrict__ ffn1_w, const float* __restrict__ ffn1_b,
    const float* __restrict__ ffn2_w, const float* __restrict__ ffn2_b,
    const float* __restrict__ fs_w,  const float* __restrict__ fs_b,
    const float* __restrict__ head_w, const float* __restrict__ head_b,
    float* __restrict__ out, long long nrows) {
  const long long gid = (long long)blockIdx.x * BS + threadIdx.x;
  const long long row0 = gid * 4;
  if (row0 >= nrows) return;
  // clamped row indices (tail threads re-compute duplicate rows)
  const long long rA = row0;
  const long long rB = (row0 + 1 < nrows) ? row0 + 1 : nrows - 1;
  const long long rC = (row0 + 2 < nrows) ? row0 + 2 : nrows - 1;
  const long long rD = (row0 + 3 < nrows) ? row0 + 3 : nrows - 1;

  // ---- input: 4 rows x 8 floats = 8 float4 loads ----
  const float4* __restrict__ in4 = reinterpret_cast<const float4*>(inp);
  float4 aLo = in4[rA * 2 + 0], aHi = in4[rA * 2 + 1];
  float4 bLo = in4[rB * 2 + 0], bHi = in4[rB * 2 + 1];
  float4 cLo = in4[rC * 2 + 0], cHi = in4[rC * 2 + 1];
  float4 dLo = in4[rD * 2 + 0], dHi = in4[rD * 2 + 1];
  f32x4 x0 = {aLo.x, bLo.x, cLo.x, dLo.x};
  f32x4 x1 = {aLo.y, bLo.y, cLo.y, dLo.y};
  f32x4 x2 = {aLo.z, bLo.z, cLo.z, dLo.z};
  f32x4 x3 = {aLo.w, bLo.w, cLo.w, dLo.w};
  f32x4 x4 = {aHi.x, bHi.x, cHi.x, dHi.x};
  f32x4 x5 = {aHi.y, bHi.y, cHi.y, dHi.y};
  f32x4 x6 = {aHi.z, bHi.z, cHi.z, dHi.z};
  f32x4 x7 = {aHi.w, bHi.w, cHi.w, dHi.w};

  // ---- fm: 8 -> 16, tanh ----
#define LFM(O) tanh_pade(D8(fm_w, fm_b, O, x0, x1, x2, x3, x4, x5, x6, x7))
  f32x4 a0 = LFM(0),  a1 = LFM(1),  a2 = LFM(2),  a3 = LFM(3);
  f32x4 a4 = LFM(4),  a5 = LFM(5),  a6 = LFM(6),  a7 = LFM(7);
  f32x4 a8 = LFM(8),  a9 = LFM(9),  aa = LFM(10), ab = LFM(11);
  f32x4 ac = LFM(12), ad = LFM(13), ae = LFM(14), af = LFM(15);

  // ---- c1: 16 -> 16, tanh ----
#define LC1(O) tanh_pade(D16(c1_w, c1_b, O, a0,a1,a2,a3,a4,a5,a6,a7,a8,a9,aa,ab,ac,ad,ae,af))
  f32x4 b0 = LC1(0),  b1 = LC1(1),  b2 = LC1(2),  b3 = LC1(3);
  f32x4 b4 = LC1(4),  b5 = LC1(5),  b6 = LC1(6),  b7 = LC1(7);
  f32x4 b8 = LC1(8),  b9 = LC1(9),  ba = LC1(10), bb = LC1(11);
  f32x4 bc = LC1(12), bd = LC1(13), be = LC1(14), bf = LC1(15);

  // ---- p1: 16 -> 12, tanh ----
#define LP1(O) tanh_pade(D16(p1_w, p1_b, O, b0,b1,b2,b3,b4,b5,b6,b7,b8,b9,ba,bb,bc,bd,be,bf))
  f32x4 c0 = LP1(0),  c1 = LP1(1),  c2 = LP1(2),  c3 = LP1(3);
  f32x4 c4 = LP1(4),  c5 = LP1(5),  c6 = LP1(6),  c7 = LP1(7);
  f32x4 c8 = LP1(8),  c9 = LP1(9),  ca = LP1(10), cb = LP1(11);

  // ---- c2: 12 -> 8, tanh ----
#define LC2(O) tanh_pade(D12(c2_w, c2_b, O, c0,c1,c2,c3,c4,c5,c6,c7,c8,c9,ca,cb))
  f32x4 d0 = LC2(0), d1 = LC2(1), d2 = LC2(2), d3 = LC2(3);
  f32x4 d4 = LC2(4), d5 = LC2(5), d6 = LC2(6), d7 = LC2(7);

  // ---- p2: 8 -> 4, tanh ----
#define LP2(O) tanh_pade(D8(p2_w, p2_b, O, d0, d1, d2, d3, d4, d5, d6, d7))
  f32x4 e0 = LP2(0), e1 = LP2(1), e2 = LP2(2), e3 = LP2(3);

  // ---- c3: 4 -> 4, tanh  (xs) ----
  f32x4 s0 = tanh_pade(D4(c3_w, c3_b, 0, e0, e1, e2, e3));
  f32x4 s1 = tanh_pade(D4(c3_w, c3_b, 1, e0, e1, e2, e3));
  f32x4 s2 = tanh_pade(D4(c3_w, c3_b, 2, e0, e1, e2, e3));
  f32x4 s3 = tanh_pade(D4(c3_w, c3_b, 3, e0, e1, e2, e3));

  // ---- attention, seq len 1: softmax == 1 -> out == v; attn_out = o(v(xs)) ----
  f32x4 v0 = D4(v_w, v_b, 0, s0, s1, s2, s3);
  f32x4 v1 = D4(v_w, v_b, 1, s0, s1, s2, s3);
  f32x4 v2 = D4(v_w, v_b, 2, s0, s1, s2, s3);
  f32x4 v3 = D4(v_w, v_b, 3, s0, s1, s2, s3);
  f32x4 o0 = D4(o_w, o_b, 0, v0, v1, v2, v3);
  f32x4 o1 = D4(o_w, o_b, 1, v0, v1, v2, v3);
  f32x4 o2 = D4(o_w, o_b, 2, v0, v1, v2, v3);
  f32x4 o3 = D4(o_w, o_b, 3, v0, v1, v2, v3);

  // ---- residual + LN1 ----
  f32x4 t0 = s0 + o0, t1 = s1 + o1, t2 = s2 + o2, t3 = s3 + o3;
  f32x4 mu = (t0 + t1 + t2 + t3) * 0.25f;
  f32x4 q0 = t0 - mu, q1 = t1 - mu, q2 = t2 - mu, q3 = t3 - mu;
  f32x4 var = (q0 * q0 + q1 * q1 + q2 * q2 + q3 * q3) * 0.25f + 1e-5f;
  f32x4 inv;
#pragma unroll
  for (int e = 0; e < 4; ++e) inv[e] = __builtin_amdgcn_rsqf(var[e]);
  f32x4 n0 = q0 * inv * ln1_w[0] + ln1_b[0];
  f32x4 n1 = q1 * inv * ln1_w[1] + ln1_b[1];
  f32x4 n2 = q2 * inv * ln1_w[2] + ln1_b[2];
  f32x4 n3 = q3 * inv * ln1_w[3] + ln1_b[3];

  // ---- FFN: relu(4->8) -> 8->4 ----
#define LF1(O) relu4(D4(ffn1_w, ffn1_b, O, n0, n1, n2, n3))
  f32x4 f0 = LF1(0), f1 = LF1(1), f2 = LF1(2), f3 = LF1(3);
  f32x4 f4 = LF1(4), f5 = LF1(5), f6 = LF1(6), f7 = LF1(7);
  f32x4 g0 = D8(ffn2_w, ffn2_b, 0, f0, f1, f2, f3, f4, f5, f6, f7);
  f32x4 g1 = D8(ffn2_w, ffn2_b, 1, f0, f1, f2, f3, f4, f5, f6, f7);
  f32x4 g2 = D8(ffn2_w, ffn2_b, 2, f0, f1, f2, f3, f4, f5, f6, f7);
  f32x4 g3 = D8(ffn2_w, ffn2_b, 3, f0, f1, f2, f3, f4, f5, f6, f7);

  // ---- residual + LN2 ----
  f32x4 u0 = n0 + g0, u1 = n1 + g1, u2 = n2 + g2, u3 = n3 + g3;
  f32x4 mu2 = (u0 + u1 + u2 + u3) * 0.25f;
  f32x4 w0 = u0 - mu2, w1 = u1 - mu2, w2 = u2 - mu2, w3 = u3 - mu2;
  f32x4 var2 = (w0 * w0 + w1 * w1 + w2 * w2 + w3 * w3) * 0.25f + 1e-5f;
  f32x4 inv2;
#pragma unroll
  for (int e = 0; e < 4; ++e) inv2[e] = __builtin_amdgcn_rsqf(var2[e]);
  f32x4 m0 = w0 * inv2 * ln2_w[0] + ln2_b[0];
  f32x4 m1 = w1 * inv2 * ln2_w[1] + ln2_b[1];
  f32x4 m2 = w2 * inv2 * ln2_w[2] + ln2_b[2];
  f32x4 m3 = w3 * inv2 * ln2_w[3] + ln2_b[3];

  // ---- final scale: tanh(fs)*1.5+0.2, head, sigmoid ----
  f32x4 h0 = tanh_pade(D4(fs_w, fs_b, 0, m0, m1, m2, m3)) * 1.5f + 0.2f;
  f32x4 h1 = tanh_pade(D4(fs_w, fs_b, 1, m0, m1, m2, m3)) * 1.5f + 0.2f;
  f32x4 h2 = tanh_pade(D4(fs_w, fs_b, 2, m0, m1, m2, m3)) * 1.5f + 0.2f;
  f32x4 h3 = tanh_pade(D4(fs_w, fs_b, 3, m0, m1, m2, m3)) * 1.5f + 0.2f;
  f32x4 y = pkfma(head_w[3], h3,
            pkfma(head_w[2], h2,
            pkfma(head_w[1], h1,
            pkfma(head_w[0], h0, splat4(head_b[0])))));
  y = fast_sigmoid4(y);

  if (row0 + 3 < nrows) {
    reinterpret_cast<float4*>(out)[gid] = float4{y[0], y[1], y[2], y[3]};
  } else {
    out[rA] = y[0];
    if (rB > rA) out[rB] = y[1];
    if (rC > rB) out[rC] = y[2];
    if (rD > rC) out[rD] = y[3];
  }
}

extern "C" void kernel_launch(void* const* d_in, const int* in_sizes, int n_in,
                              void* d_out, int out_size, void* d_ws, size_t ws_size,
                              hipStream_t stream) {
  const float* inp = (const float*)d_in[0];
  long long nrows = (long long)in_sizes[0] / 8;
  long long nthreads = (nrows + 3) / 4;
  dim3 grid((unsigned)((nthreads + BS - 1) / BS)), block(BS);
  qcnn_pade<<<grid, block, 0, stream>>>(
      inp,
      (const float*)d_in[1],  (const float*)d_in[2],   // fm
      (const float*)d_in[3],  (const float*)d_in[4],   // c1
      (const float*)d_in[5],  (const float*)d_in[6],   // p1
      (const float*)d_in[7],  (const float*)d_in[8],   // c2
      (const float*)d_in[9],  (const float*)d_in[10],  // p2
      (const float*)d_in[11], (const float*)d_in[12],  // c3
      (const float*)d_in[17], (const float*)d_in[18],  // v (q/k dead: softmax over len-1 == 1)
      (const float*)d_in[19], (const float*)d_in[20],  // o
      (const float*)d_in[21], (const float*)d_in[22],  // ln1
      (const float*)d_in[23], (const float*)d_in[24],  // ln2
      (const float*)d_in[25], (const float*)d_in[26],  // ffn1
      (const float*)d_in[27], (const float*)d_in[28],  // ffn2
      (const float*)d_in[29], (const float*)d_in[30],  // fs
      (const float*)d_in[31], (const float*)d_in[32],  // head
      (float*)d_out, nrows);
}

// Round 8
// 79.574 us; speedup vs baseline: 1.0085x; 1.0085x over previous
//
#include <hip/hip_runtime.h>

#define BS 256

typedef float f32x2 __attribute__((ext_vector_type(2)));
typedef unsigned int u32x2 __attribute__((ext_vector_type(2)));

__device__ __forceinline__ f32x2 splat2(float v) {
  f32x2 r; r[0] = v; r[1] = v; return r;
}
__device__ __forceinline__ f32x2 pkfma(float w, f32x2 x, f32x2 a) {
  return __builtin_elementwise_fma(splat2(w), x, a);
}

// tanh via Pade[7/6] continued-fraction convergent, zero transcendentals.
// tanh(x) ~= x(t^3+378t^2+17325t+135135)/(28t^3+3150t^2+62370t+135135), t=x^2.
// |err|<=~1e-4; ratio overshoots 1 only past |x|~4.9 -> med3 output clamp makes
// the tail exact. No input clamp needed (ratio>1 for all big x, d>0 always).
// Division: bit-hack rcp init + 3 Newton iters (proven at absmax floor in r7).
__device__ __forceinline__ f32x2 tanh_pade2(f32x2 x) {
  f32x2 t = x * x;
  f32x2 n = t + 378.0f;
  n = __builtin_elementwise_fma(n, t, splat2(17325.0f));
  n = __builtin_elementwise_fma(n, t, splat2(135135.0f));
  n = n * x;
  f32x2 d = __builtin_elementwise_fma(t, splat2(28.0f), splat2(3150.0f));
  d = __builtin_elementwise_fma(d, t, splat2(62370.0f));
  d = __builtin_elementwise_fma(d, t, splat2(135135.0f));
  u32x2 bi = __builtin_bit_cast(u32x2, d);
  u32x2 yi = 0x7EF311C3u - bi;
  f32x2 y = __builtin_bit_cast(f32x2, yi);
#pragma unroll
  for (int it = 0; it < 3; ++it) {
    f32x2 u = __builtin_elementwise_fma(-d, y, splat2(2.0f));
    y = y * u;
  }
  f32x2 r = n * y;
  r[0] = __builtin_amdgcn_fmed3f(r[0], -1.0f, 1.0f);
  r[1] = __builtin_amdgcn_fmed3f(r[1], -1.0f, 1.0f);
  return r;
}

// sigmoid(x) = 0.5*(1 + tanh(x/2)) -- reuses Pade, no transcendentals
__device__ __forceinline__ f32x2 sigmoid_pade2(f32x2 x) {
  f32x2 h = tanh_pade2(x * 0.5f);
  return __builtin_elementwise_fma(h, splat2(0.5f), splat2(0.5f));
}

// rsqrt via bit-hack + 2 Newton iterations (rel err ~5e-6; LN tolerance huge)
__device__ __forceinline__ f32x2 fast_rsqrt2(f32x2 d) {
  u32x2 bi = __builtin_bit_cast(u32x2, d);
  u32x2 yi;
  yi[0] = 0x5f3759dfu - (bi[0] >> 1);
  yi[1] = 0x5f3759dfu - (bi[1] >> 1);
  f32x2 y = __builtin_bit_cast(f32x2, yi);
#pragma unroll
  for (int it = 0; it < 2; ++it) {
    f32x2 h = d * y;
    h = h * y;
    h = __builtin_elementwise_fma(h, splat2(-0.5f), splat2(1.5f));
    y = y * h;
  }
  return y;
}

__device__ __forceinline__ f32x2 relu2(f32x2 x) {
  return __builtin_elementwise_max(x, splat2(0.0f));
}

// nested packed-fma dot products; weight indices are literals -> uniform s_loads
#define D4(W, B, O, p0, p1, p2, p3)                                            \
  pkfma((W)[(O)*4 + 0], p0,                                                    \
  pkfma((W)[(O)*4 + 1], p1,                                                    \
  pkfma((W)[(O)*4 + 2], p2,                                                    \
  pkfma((W)[(O)*4 + 3], p3, splat2((B)[O])))))

#define D8(W, B, O, p0, p1, p2, p3, p4, p5, p6, p7)                            \
  pkfma((W)[(O)*8 + 0], p0,                                                    \
  pkfma((W)[(O)*8 + 1], p1,                                                    \
  pkfma((W)[(O)*8 + 2], p2,                                                    \
  pkfma((W)[(O)*8 + 3], p3,                                                    \
  pkfma((W)[(O)*8 + 4], p4,                                                    \
  pkfma((W)[(O)*8 + 5], p5,                                                    \
  pkfma((W)[(O)*8 + 6], p6,                                                    \
  pkfma((W)[(O)*8 + 7], p7, splat2((B)[O])))))))))

#define D12(W, B, O, p0, p1, p2, p3, p4, p5, p6, p7, p8, p9, pa, pb)           \
  pkfma((W)[(O)*12 + 0], p0,                                                   \
  pkfma((W)[(O)*12 + 1], p1,                                                   \
  pkfma((W)[(O)*12 + 2], p2,                                                   \
  pkfma((W)[(O)*12 + 3], p3,                                                   \
  pkfma((W)[(O)*12 + 4], p4,                                                   \
  pkfma((W)[(O)*12 + 5], p5,                                                   \
  pkfma((W)[(O)*12 + 6], p6,                                                   \
  pkfma((W)[(O)*12 + 7], p7,                                                   \
  pkfma((W)[(O)*12 + 8], p8,                                                   \
  pkfma((W)[(O)*12 + 9], p9,                                                   \
  pkfma((W)[(O)*12 +10], pa,                                                   \
  pkfma((W)[(O)*12 +11], pb, splat2((B)[O])))))))))))))

#define D16(W, B, O, p0, p1, p2, p3, p4, p5, p6, p7, p8, p9, pa, pb, pc, pd, pe, pf) \
  pkfma((W)[(O)*16 + 0], p0,                                                   \
  pkfma((W)[(O)*16 + 1], p1,                                                   \
  pkfma((W)[(O)*16 + 2], p2,                                                   \
  pkfma((W)[(O)*16 + 3], p3,                                                   \
  pkfma((W)[(O)*16 + 4], p4,                                                   \
  pkfma((W)[(O)*16 + 5], p5,                                                   \
  pkfma((W)[(O)*16 + 6], p6,                                                   \
  pkfma((W)[(O)*16 + 7], p7,                                                   \
  pkfma((W)[(O)*16 + 8], p8,                                                   \
  pkfma((W)[(O)*16 + 9], p9,                                                   \
  pkfma((W)[(O)*16 +10], pa,                                                   \
  pkfma((W)[(O)*16 +11], pb,                                                   \
  pkfma((W)[(O)*16 +12], pc,                                                   \
  pkfma((W)[(O)*16 +13], pd,                                                   \
  pkfma((W)[(O)*16 +14], pe,                                                   \
  pkfma((W)[(O)*16 +15], pf, splat2((B)[O])))))))))))))))))

__global__ void __launch_bounds__(BS) qcnn_pade2(
    const float* __restrict__ inp,
    const float* __restrict__ fm_w,  const float* __restrict__ fm_b,
    const float* __restrict__ c1_w,  const float* __restrict__ c1_b,
    const float* __restrict__ p1_w,  const float* __restrict__ p1_b,
    const float* __restrict__ c2_w,  const float* __restrict__ c2_b,
    const float* __restrict__ p2_w,  const float* __restrict__ p2_b,
    const float* __restrict__ c3_w,  const float* __restrict__ c3_b,
    const float* __restrict__ v_w,   const float* __restrict__ v_b,
    const float* __restrict__ o_w,   const float* __restrict__ o_b,
    const float* __restrict__ ln1_w, const float* __restrict__ ln1_b,
    const float* __restrict__ ln2_w, const float* __restrict__ ln2_b,
    const float* __restrict__ ffn1_w, const float* __restrict__ ffn1_b,
    const float* __restrict__ ffn2_w, const float* __restrict__ ffn2_b,
    const float* __restrict__ fs_w,  const float* __restrict__ fs_b,
    const float* __restrict__ head_w, const float* __restrict__ head_b,
    float* __restrict__ out, long long nrows) {
  const long long gid = (long long)blockIdx.x * BS + threadIdx.x;
  const long long row0 = gid * 2;
  if (row0 >= nrows) return;
  const bool ok1 = (row0 + 1) < nrows;

  // ---- input: 2 rows x 8 floats = 4 float4 loads ----
  const float4* __restrict__ in4 = reinterpret_cast<const float4*>(inp);
  float4 r0lo = in4[gid * 4 + 0];
  float4 r0hi = in4[gid * 4 + 1];
  float4 r1lo, r1hi;
  if (ok1) {
    r1lo = in4[gid * 4 + 2];
    r1hi = in4[gid * 4 + 3];
  } else {
    r1lo = float4{0.f, 0.f, 0.f, 0.f};
    r1hi = float4{0.f, 0.f, 0.f, 0.f};
  }
  f32x2 x0 = {r0lo.x, r1lo.x}, x1 = {r0lo.y, r1lo.y};
  f32x2 x2 = {r0lo.z, r1lo.z}, x3 = {r0lo.w, r1lo.w};
  f32x2 x4 = {r0hi.x, r1hi.x}, x5 = {r0hi.y, r1hi.y};
  f32x2 x6 = {r0hi.z, r1hi.z}, x7 = {r0hi.w, r1hi.w};

  // ---- fm: 8 -> 16, tanh ----
#define LFM(O) tanh_pade2(D8(fm_w, fm_b, O, x0, x1, x2, x3, x4, x5, x6, x7))
  f32x2 a0 = LFM(0),  a1 = LFM(1),  a2 = LFM(2),  a3 = LFM(3);
  f32x2 a4 = LFM(4),  a5 = LFM(5),  a6 = LFM(6),  a7 = LFM(7);
  f32x2 a8 = LFM(8),  a9 = LFM(9),  aa = LFM(10), ab = LFM(11);
  f32x2 ac = LFM(12), ad = LFM(13), ae = LFM(14), af = LFM(15);

  // ---- c1: 16 -> 16, tanh ----
#define LC1(O) tanh_pade2(D16(c1_w, c1_b, O, a0,a1,a2,a3,a4,a5,a6,a7,a8,a9,aa,ab,ac,ad,ae,af))
  f32x2 b0 = LC1(0),  b1 = LC1(1),  b2 = LC1(2),  b3 = LC1(3);
  f32x2 b4 = LC1(4),  b5 = LC1(5),  b6 = LC1(6),  b7 = LC1(7);
  f32x2 b8 = LC1(8),  b9 = LC1(9),  ba = LC1(10), bb = LC1(11);
  f32x2 bc = LC1(12), bd = LC1(13), be = LC1(14), bf = LC1(15);

  // ---- p1: 16 -> 12, tanh ----
#define LP1(O) tanh_pade2(D16(p1_w, p1_b, O, b0,b1,b2,b3,b4,b5,b6,b7,b8,b9,ba,bb,bc,bd,be,bf))
  f32x2 c0 = LP1(0),  c1 = LP1(1),  c2 = LP1(2),  c3 = LP1(3);
  f32x2 c4 = LP1(4),  c5 = LP1(5),  c6 = LP1(6),  c7 = LP1(7);
  f32x2 c8 = LP1(8),  c9 = LP1(9),  ca = LP1(10), cb = LP1(11);

  // ---- c2: 12 -> 8, tanh ----
#define LC2(O) tanh_pade2(D12(c2_w, c2_b, O, c0,c1,c2,c3,c4,c5,c6,c7,c8,c9,ca,cb))
  f32x2 d0 = LC2(0), d1 = LC2(1), d2 = LC2(2), d3 = LC2(3);
  f32x2 d4 = LC2(4), d5 = LC2(5), d6 = LC2(6), d7 = LC2(7);

  // ---- p2: 8 -> 4, tanh ----
#define LP2(O) tanh_pade2(D8(p2_w, p2_b, O, d0, d1, d2, d3, d4, d5, d6, d7))
  f32x2 e0 = LP2(0), e1 = LP2(1), e2 = LP2(2), e3 = LP2(3);

  // ---- c3: 4 -> 4, tanh  (xs) ----
  f32x2 s0 = tanh_pade2(D4(c3_w, c3_b, 0, e0, e1, e2, e3));
  f32x2 s1 = tanh_pade2(D4(c3_w, c3_b, 1, e0, e1, e2, e3));
  f32x2 s2 = tanh_pade2(D4(c3_w, c3_b, 2, e0, e1, e2, e3));
  f32x2 s3 = tanh_pade2(D4(c3_w, c3_b, 3, e0, e1, e2, e3));

  // ---- attention, seq len 1: softmax == 1 -> out == v; attn_out = o(v(xs)) ----
  f32x2 v0 = D4(v_w, v_b, 0, s0, s1, s2, s3);
  f32x2 v1 = D4(v_w, v_b, 1, s0, s1, s2, s3);
  f32x2 v2 = D4(v_w, v_b, 2, s0, s1, s2, s3);
  f32x2 v3 = D4(v_w, v_b, 3, s0, s1, s2, s3);
  f32x2 o0 = D4(o_w, o_b, 0, v0, v1, v2, v3);
  f32x2 o1 = D4(o_w, o_b, 1, v0, v1, v2, v3);
  f32x2 o2 = D4(o_w, o_b, 2, v0, v1, v2, v3);
  f32x2 o3 = D4(o_w, o_b, 3, v0, v1, v2, v3);

  // ---- residual + LN1 ----
  f32x2 t0 = s0 + o0, t1 = s1 + o1, t2 = s2 + o2, t3 = s3 + o3;
  f32x2 mu = (t0 + t1 + t2 + t3) * 0.25f;
  f32x2 q0 = t0 - mu, q1 = t1 - mu, q2 = t2 - mu, q3 = t3 - mu;
  f32x2 var = (q0 * q0 + q1 * q1 + q2 * q2 + q3 * q3) * 0.25f + 1e-5f;
  f32x2 inv = fast_rsqrt2(var);
  f32x2 n0 = q0 * inv * ln1_w[0] + ln1_b[0];
  f32x2 n1 = q1 * inv * ln1_w[1] + ln1_b[1];
  f32x2 n2 = q2 * inv * ln1_w[2] + ln1_b[2];
  f32x2 n3 = q3 * inv * ln1_w[3] + ln1_b[3];

  // ---- FFN: relu(4->8) -> 8->4 ----
#define LF1(O) relu2(D4(ffn1_w, ffn1_b, O, n0, n1, n2, n3))
  f32x2 f0 = LF1(0), f1 = LF1(1), f2 = LF1(2), f3 = LF1(3);
  f32x2 f4 = LF1(4), f5 = LF1(5), f6 = LF1(6), f7 = LF1(7);
  f32x2 g0 = D8(ffn2_w, ffn2_b, 0, f0, f1, f2, f3, f4, f5, f6, f7);
  f32x2 g1 = D8(ffn2_w, ffn2_b, 1, f0, f1, f2, f3, f4, f5, f6, f7);
  f32x2 g2 = D8(ffn2_w, ffn2_b, 2, f0, f1, f2, f3, f4, f5, f6, f7);
  f32x2 g3 = D8(ffn2_w, ffn2_b, 3, f0, f1, f2, f3, f4, f5, f6, f7);

  // ---- residual + LN2 ----
  f32x2 u0 = n0 + g0, u1 = n1 + g1, u2 = n2 + g2, u3 = n3 + g3;
  f32x2 mu2 = (u0 + u1 + u2 + u3) * 0.25f;
  f32x2 w0 = u0 - mu2, w1 = u1 - mu2, w2 = u2 - mu2, w3 = u3 - mu2;
  f32x2 var2 = (w0 * w0 + w1 * w1 + w2 * w2 + w3 * w3) * 0.25f + 1e-5f;
  f32x2 inv2 = fast_rsqrt2(var2);
  f32x2 m0 = w0 * inv2 * ln2_w[0] + ln2_b[0];
  f32x2 m1 = w1 * inv2 * ln2_w[1] + ln2_b[1];
  f32x2 m2 = w2 * inv2 * ln2_w[2] + ln2_b[2];
  f32x2 m3 = w3 * inv2 * ln2_w[3] + ln2_b[3];

  // ---- final scale: tanh(fs)*1.5+0.2, head, sigmoid ----
  f32x2 h0 = tanh_pade2(D4(fs_w, fs_b, 0, m0, m1, m2, m3)) * 1.5f + 0.2f;
  f32x2 h1 = tanh_pade2(D4(fs_w, fs_b, 1, m0, m1, m2, m3)) * 1.5f + 0.2f;
  f32x2 h2 = tanh_pade2(D4(fs_w, fs_b, 2, m0, m1, m2, m3)) * 1.5f + 0.2f;
  f32x2 h3 = tanh_pade2(D4(fs_w, fs_b, 3, m0, m1, m2, m3)) * 1.5f + 0.2f;
  f32x2 y = pkfma(head_w[3], h3,
            pkfma(head_w[2], h2,
            pkfma(head_w[1], h1,
            pkfma(head_w[0], h0, splat2(head_b[0])))));
  y = sigmoid_pade2(y);

  if (ok1) {
    reinterpret_cast<float2*>(out)[gid] = make_float2(y[0], y[1]);
  } else {
    out[row0] = y[0];
  }
}

extern "C" void kernel_launch(void* const* d_in, const int* in_sizes, int n_in,
                              void* d_out, int out_size, void* d_ws, size_t ws_size,
                              hipStream_t stream) {
  const float* inp = (const float*)d_in[0];
  long long nrows = (long long)in_sizes[0] / 8;
  long long nthreads = (nrows + 1) / 2;
  dim3 grid((unsigned)((nthreads + BS - 1) / BS)), block(BS);
  qcnn_pade2<<<grid, block, 0, stream>>>(
      inp,
      (const float*)d_in[1],  (const float*)d_in[2],   // fm
      (const float*)d_in[3],  (const float*)d_in[4],   // c1
      (const float*)d_in[5],  (const float*)d_in[6],   // p1
      (const float*)d_in[7],  (const float*)d_in[8],   // c2
      (const float*)d_in[9],  (const float*)d_in[10],  // p2
      (const float*)d_in[11], (const float*)d_in[12],  // c3
      (const float*)d_in[17], (const float*)d_in[18],  // v (q/k dead: softmax over len-1 == 1)
      (const float*)d_in[19], (const float*)d_in[20],  // o
      (const float*)d_in[21], (const float*)d_in[22],  // ln1
      (const float*)d_in[23], (const float*)d_in[24],  // ln2
      (const float*)d_in[25], (const float*)d_in[26],  // ffn1
      (const float*)d_in[27], (const float*)d_in[28],  // ffn2
      (const float*)d_in[29], (const float*)d_in[30],  // fs
      (const float*)d_in[31], (const float*)d_in[32],  // head
      (float*)d_out, nrows);
}

// Round 9
// 61.756 us; speedup vs baseline: 1.2995x; 1.2885x over previous
//
#include <hip/hip_runtime.h>

#define BS 256

typedef float f32x4 __attribute__((ext_vector_type(4)));

__device__ __forceinline__ f32x4 splat4(float v) {
  f32x4 r; r[0] = v; r[1] = v; r[2] = v; r[3] = v; return r;
}
__device__ __forceinline__ f32x4 pkfma(float w, f32x4 x, f32x4 a) {
  return __builtin_elementwise_fma(splat4(w), x, a);
}

// tanh(x) = 1 - 2/(exp2(2*log2e*x)+1); exact saturation via rcp(inf)=0.
// r4-proven math (absmax at bf16 floor). Trans ops are cheap (~4-6cyc/inst).
__device__ __forceinline__ f32x4 fast_tanh4(f32x4 x) {
  f32x4 z = x * 2.8853900817779268f;
  f32x4 t;
#pragma unroll
  for (int e = 0; e < 4; ++e) t[e] = __builtin_amdgcn_exp2f(z[e]);
  f32x4 tp1 = t + 1.0f;
  f32x4 r;
#pragma unroll
  for (int e = 0; e < 4; ++e) r[e] = __builtin_amdgcn_rcpf(tp1[e]);
  return __builtin_elementwise_fma(splat4(-2.0f), r, splat4(1.0f));
}
__device__ __forceinline__ f32x4 fast_sigmoid4(f32x4 x) {
  f32x4 z = x * -1.4426950408889634f;
  f32x4 t;
#pragma unroll
  for (int e = 0; e < 4; ++e) t[e] = __builtin_amdgcn_exp2f(z[e]);
  f32x4 tp1 = t + 1.0f;
  f32x4 r;
#pragma unroll
  for (int e = 0; e < 4; ++e) r[e] = __builtin_amdgcn_rcpf(tp1[e]);
  return r;
}
__device__ __forceinline__ f32x4 relu4(f32x4 x) {
  return __builtin_elementwise_max(x, splat4(0.0f));
}

// nested packed-fma dot products; weight indices are literals -> uniform s_loads
#define D4(W, B, O, p0, p1, p2, p3)                                            \
  pkfma((W)[(O)*4 + 0], p0,                                                    \
  pkfma((W)[(O)*4 + 1], p1,                                                    \
  pkfma((W)[(O)*4 + 2], p2,                                                    \
  pkfma((W)[(O)*4 + 3], p3, splat4((B)[O])))))

#define D8(W, B, O, p0, p1, p2, p3, p4, p5, p6, p7)                            \
  pkfma((W)[(O)*8 + 0], p0,                                                    \
  pkfma((W)[(O)*8 + 1], p1,                                                    \
  pkfma((W)[(O)*8 + 2], p2,                                                    \
  pkfma((W)[(O)*8 + 3], p3,                                                    \
  pkfma((W)[(O)*8 + 4], p4,                                                    \
  pkfma((W)[(O)*8 + 5], p5,                                                    \
  pkfma((W)[(O)*8 + 6], p6,                                                    \
  pkfma((W)[(O)*8 + 7], p7, splat4((B)[O])))))))))

#define D12(W, B, O, p0, p1, p2, p3, p4, p5, p6, p7, p8, p9, pa, pb)           \
  pkfma((W)[(O)*12 + 0], p0,                                                   \
  pkfma((W)[(O)*12 + 1], p1,                                                   \
  pkfma((W)[(O)*12 + 2], p2,                                                   \
  pkfma((W)[(O)*12 + 3], p3,                                                   \
  pkfma((W)[(O)*12 + 4], p4,                                                   \
  pkfma((W)[(O)*12 + 5], p5,                                                   \
  pkfma((W)[(O)*12 + 6], p6,                                                   \
  pkfma((W)[(O)*12 + 7], p7,                                                   \
  pkfma((W)[(O)*12 + 8], p8,                                                   \
  pkfma((W)[(O)*12 + 9], p9,                                                   \
  pkfma((W)[(O)*12 +10], pa,                                                   \
  pkfma((W)[(O)*12 +11], pb, splat4((B)[O])))))))))))))

#define D16(W, B, O, p0, p1, p2, p3, p4, p5, p6, p7, p8, p9, pa, pb, pc, pd, pe, pf) \
  pkfma((W)[(O)*16 + 0], p0,                                                   \
  pkfma((W)[(O)*16 + 1], p1,                                                   \
  pkfma((W)[(O)*16 + 2], p2,                                                   \
  pkfma((W)[(O)*16 + 3], p3,                                                   \
  pkfma((W)[(O)*16 + 4], p4,                                                   \
  pkfma((W)[(O)*16 + 5], p5,                                                   \
  pkfma((W)[(O)*16 + 6], p6,                                                   \
  pkfma((W)[(O)*16 + 7], p7,                                                   \
  pkfma((W)[(O)*16 + 8], p8,                                                   \
  pkfma((W)[(O)*16 + 9], p9,                                                   \
  pkfma((W)[(O)*16 +10], pa,                                                   \
  pkfma((W)[(O)*16 +11], pb,                                                   \
  pkfma((W)[(O)*16 +12], pc,                                                   \
  pkfma((W)[(O)*16 +13], pd,                                                   \
  pkfma((W)[(O)*16 +14], pe,                                                   \
  pkfma((W)[(O)*16 +15], pf, splat4((B)[O])))))))))))))))))

__global__ void __launch_bounds__(BS) qcnn_x4(
    const float* __restrict__ inp,
    const float* __restrict__ fm_w,  const float* __restrict__ fm_b,
    const float* __restrict__ c1_w,  const float* __restrict__ c1_b,
    const float* __restrict__ p1_w,  const float* __restrict__ p1_b,
    const float* __restrict__ c2_w,  const float* __restrict__ c2_b,
    const float* __restrict__ p2_w,  const float* __restrict__ p2_b,
    const float* __restrict__ c3_w,  const float* __restrict__ c3_b,
    const float* __restrict__ v_w,   const float* __restrict__ v_b,
    const float* __restrict__ o_w,   const float* __restrict__ o_b,
    const float* __restrict__ ln1_w, const float* __restrict__ ln1_b,
    const float* __restrict__ ln2_w, const float* __restrict__ ln2_b,
    const float* __restrict__ ffn1_w, const float* __restrict__ ffn1_b,
    const float* __restrict__ ffn2_w, const float* __restrict__ ffn2_b,
    const float* __restrict__ fs_w,  const float* __restrict__ fs_b,
    const float* __restrict__ head_w, const float* __restrict__ head_b,
    float* __restrict__ out, long long nrows) {
  const long long gid = (long long)blockIdx.x * BS + threadIdx.x;
  const long long row0 = gid * 4;
  if (row0 >= nrows) return;
  // clamped row indices (tail threads recompute duplicate rows; r7-proven)
  const long long rA = row0;
  const long long rB = (row0 + 1 < nrows) ? row0 + 1 : nrows - 1;
  const long long rC = (row0 + 2 < nrows) ? row0 + 2 : nrows - 1;
  const long long rD = (row0 + 3 < nrows) ? row0 + 3 : nrows - 1;

  // ---- input: 4 rows x 8 floats = 8 float4 loads ----
  const float4* __restrict__ in4 = reinterpret_cast<const float4*>(inp);
  float4 aLo = in4[rA * 2 + 0], aHi = in4[rA * 2 + 1];
  float4 bLo = in4[rB * 2 + 0], bHi = in4[rB * 2 + 1];
  float4 cLo = in4[rC * 2 + 0], cHi = in4[rC * 2 + 1];
  float4 dLo = in4[rD * 2 + 0], dHi = in4[rD * 2 + 1];
  f32x4 x0 = {aLo.x, bLo.x, cLo.x, dLo.x};
  f32x4 x1 = {aLo.y, bLo.y, cLo.y, dLo.y};
  f32x4 x2 = {aLo.z, bLo.z, cLo.z, dLo.z};
  f32x4 x3 = {aLo.w, bLo.w, cLo.w, dLo.w};
  f32x4 x4 = {aHi.x, bHi.x, cHi.x, dHi.x};
  f32x4 x5 = {aHi.y, bHi.y, cHi.y, dHi.y};
  f32x4 x6 = {aHi.z, bHi.z, cHi.z, dHi.z};
  f32x4 x7 = {aHi.w, bHi.w, cHi.w, dHi.w};

  // ---- fm: 8 -> 16, tanh ----
#define LFM(O) fast_tanh4(D8(fm_w, fm_b, O, x0, x1, x2, x3, x4, x5, x6, x7))
  f32x4 a0 = LFM(0),  a1 = LFM(1),  a2 = LFM(2),  a3 = LFM(3);
  f32x4 a4 = LFM(4),  a5 = LFM(5),  a6 = LFM(6),  a7 = LFM(7);
  f32x4 a8 = LFM(8),  a9 = LFM(9),  aa = LFM(10), ab = LFM(11);
  f32x4 ac = LFM(12), ad = LFM(13), ae = LFM(14), af = LFM(15);

  // ---- c1: 16 -> 16, tanh ----
#define LC1(O) fast_tanh4(D16(c1_w, c1_b, O, a0,a1,a2,a3,a4,a5,a6,a7,a8,a9,aa,ab,ac,ad,ae,af))
  f32x4 b0 = LC1(0),  b1 = LC1(1),  b2 = LC1(2),  b3 = LC1(3);
  f32x4 b4 = LC1(4),  b5 = LC1(5),  b6 = LC1(6),  b7 = LC1(7);
  f32x4 b8 = LC1(8),  b9 = LC1(9),  ba = LC1(10), bb = LC1(11);
  f32x4 bc = LC1(12), bd = LC1(13), be = LC1(14), bf = LC1(15);

  // ---- p1: 16 -> 12, tanh ----
#define LP1(O) fast_tanh4(D16(p1_w, p1_b, O, b0,b1,b2,b3,b4,b5,b6,b7,b8,b9,ba,bb,bc,bd,be,bf))
  f32x4 c0 = LP1(0),  c1 = LP1(1),  c2 = LP1(2),  c3 = LP1(3);
  f32x4 c4 = LP1(4),  c5 = LP1(5),  c6 = LP1(6),  c7 = LP1(7);
  f32x4 c8 = LP1(8),  c9 = LP1(9),  ca = LP1(10), cb = LP1(11);

  // ---- c2: 12 -> 8, tanh ----
#define LC2(O) fast_tanh4(D12(c2_w, c2_b, O, c0,c1,c2,c3,c4,c5,c6,c7,c8,c9,ca,cb))
  f32x4 d0 = LC2(0), d1 = LC2(1), d2 = LC2(2), d3 = LC2(3);
  f32x4 d4 = LC2(4), d5 = LC2(5), d6 = LC2(6), d7 = LC2(7);

  // ---- p2: 8 -> 4, tanh ----
#define LP2(O) fast_tanh4(D8(p2_w, p2_b, O, d0, d1, d2, d3, d4, d5, d6, d7))
  f32x4 e0 = LP2(0), e1 = LP2(1), e2 = LP2(2), e3 = LP2(3);

  // ---- c3: 4 -> 4, tanh  (xs) ----
  f32x4 s0 = fast_tanh4(D4(c3_w, c3_b, 0, e0, e1, e2, e3));
  f32x4 s1 = fast_tanh4(D4(c3_w, c3_b, 1, e0, e1, e2, e3));
  f32x4 s2 = fast_tanh4(D4(c3_w, c3_b, 2, e0, e1, e2, e3));
  f32x4 s3 = fast_tanh4(D4(c3_w, c3_b, 3, e0, e1, e2, e3));

  // ---- attention, seq len 1: softmax == 1 -> out == v; attn_out = o(v(xs)) ----
  f32x4 v0 = D4(v_w, v_b, 0, s0, s1, s2, s3);
  f32x4 v1 = D4(v_w, v_b, 1, s0, s1, s2, s3);
  f32x4 v2 = D4(v_w, v_b, 2, s0, s1, s2, s3);
  f32x4 v3 = D4(v_w, v_b, 3, s0, s1, s2, s3);
  f32x4 o0 = D4(o_w, o_b, 0, v0, v1, v2, v3);
  f32x4 o1 = D4(o_w, o_b, 1, v0, v1, v2, v3);
  f32x4 o2 = D4(o_w, o_b, 2, v0, v1, v2, v3);
  f32x4 o3 = D4(o_w, o_b, 3, v0, v1, v2, v3);

  // ---- residual + LN1 ----
  f32x4 t0 = s0 + o0, t1 = s1 + o1, t2 = s2 + o2, t3 = s3 + o3;
  f32x4 mu = (t0 + t1 + t2 + t3) * 0.25f;
  f32x4 q0 = t0 - mu, q1 = t1 - mu, q2 = t2 - mu, q3 = t3 - mu;
  f32x4 var = (q0 * q0 + q1 * q1 + q2 * q2 + q3 * q3) * 0.25f + 1e-5f;
  f32x4 inv;
#pragma unroll
  for (int e = 0; e < 4; ++e) inv[e] = __builtin_amdgcn_rsqf(var[e]);
  f32x4 n0 = q0 * inv * ln1_w[0] + ln1_b[0];
  f32x4 n1 = q1 * inv * ln1_w[1] + ln1_b[1];
  f32x4 n2 = q2 * inv * ln1_w[2] + ln1_b[2];
  f32x4 n3 = q3 * inv * ln1_w[3] + ln1_b[3];

  // ---- FFN: relu(4->8) -> 8->4 ----
#define LF1(O) relu4(D4(ffn1_w, ffn1_b, O, n0, n1, n2, n3))
  f32x4 f0 = LF1(0), f1 = LF1(1), f2 = LF1(2), f3 = LF1(3);
  f32x4 f4 = LF1(4), f5 = LF1(5), f6 = LF1(6), f7 = LF1(7);
  f32x4 g0 = D8(ffn2_w, ffn2_b, 0, f0, f1, f2, f3, f4, f5, f6, f7);
  f32x4 g1 = D8(ffn2_w, ffn2_b, 1, f0, f1, f2, f3, f4, f5, f6, f7);
  f32x4 g2 = D8(ffn2_w, ffn2_b, 2, f0, f1, f2, f3, f4, f5, f6, f7);
  f32x4 g3 = D8(ffn2_w, ffn2_b, 3, f0, f1, f2, f3, f4, f5, f6, f7);

  // ---- residual + LN2 ----
  f32x4 u0 = n0 + g0, u1 = n1 + g1, u2 = n2 + g2, u3 = n3 + g3;
  f32x4 mu2 = (u0 + u1 + u2 + u3) * 0.25f;
  f32x4 w0 = u0 - mu2, w1 = u1 - mu2, w2 = u2 - mu2, w3 = u3 - mu2;
  f32x4 var2 = (w0 * w0 + w1 * w1 + w2 * w2 + w3 * w3) * 0.25f + 1e-5f;
  f32x4 inv2;
#pragma unroll
  for (int e = 0; e < 4; ++e) inv2[e] = __builtin_amdgcn_rsqf(var2[e]);
  f32x4 m0 = w0 * inv2 * ln2_w[0] + ln2_b[0];
  f32x4 m1 = w1 * inv2 * ln2_w[1] + ln2_b[1];
  f32x4 m2 = w2 * inv2 * ln2_w[2] + ln2_b[2];
  f32x4 m3 = w3 * inv2 * ln2_w[3] + ln2_b[3];

  // ---- final scale: tanh(fs)*1.5+0.2, head, sigmoid ----
  f32x4 h0 = fast_tanh4(D4(fs_w, fs_b, 0, m0, m1, m2, m3)) * 1.5f + 0.2f;
  f32x4 h1 = fast_tanh4(D4(fs_w, fs_b, 1, m0, m1, m2, m3)) * 1.5f + 0.2f;
  f32x4 h2 = fast_tanh4(D4(fs_w, fs_b, 2, m0, m1, m2, m3)) * 1.5f + 0.2f;
  f32x4 h3 = fast_tanh4(D4(fs_w, fs_b, 3, m0, m1, m2, m3)) * 1.5f + 0.2f;
  f32x4 y = pkfma(head_w[3], h3,
            pkfma(head_w[2], h2,
            pkfma(head_w[1], h1,
            pkfma(head_w[0], h0, splat4(head_b[0])))));
  y = fast_sigmoid4(y);

  if (row0 + 3 < nrows) {
    reinterpret_cast<float4*>(out)[gid] = float4{y[0], y[1], y[2], y[3]};
  } else {
    out[rA] = y[0];
    if (rB > rA) out[rB] = y[1];
    if (rC > rB) out[rC] = y[2];
    if (rD > rC) out[rD] = y[3];
  }
}

extern "C" void kernel_launch(void* const* d_in, const int* in_sizes, int n_in,
                              void* d_out, int out_size, void* d_ws, size_t ws_size,
                              hipStream_t stream) {
  const float* inp = (const float*)d_in[0];
  long long nrows = (long long)in_sizes[0] / 8;
  long long nthreads = (nrows + 3) / 4;
  dim3 grid((unsigned)((nthreads + BS - 1) / BS)), block(BS);
  qcnn_x4<<<grid, block, 0, stream>>>(
      inp,
      (const float*)d_in[1],  (const float*)d_in[2],   // fm
      (const float*)d_in[3],  (const float*)d_in[4],   // c1
      (const float*)d_in[5],  (const float*)d_in[6],   // p1
      (const float*)d_in[7],  (const float*)d_in[8],   // c2
      (const float*)d_in[9],  (const float*)d_in[10],  // p2
      (const float*)d_in[11], (const float*)d_in[12],  // c3
      (const float*)d_in[17], (const float*)d_in[18],  // v (q/k dead: softmax over len-1 == 1)
      (const float*)d_in[19], (const float*)d_in[20],  // o
      (const float*)d_in[21], (const float*)d_in[22],  // ln1
      (const float*)d_in[23], (const float*)d_in[24],  // ln2
      (const float*)d_in[25], (const float*)d_in[26],  // ffn1
      (const float*)d_in[27], (const float*)d_in[28],  // ffn2
      (const float*)d_in[29], (const float*)d_in[30],  // fs
      (const float*)d_in[31], (const float*)d_in[32],  // head
      (float*)d_out, nrows);
}